// Round 6
// baseline (1766.491 us; speedup 1.0000x reference)
//
#include <hip/hip_runtime.h>

// VanillaRNN: h_{t+1} = tanh(W_hx x_t + W_hh h_t + b_h), T=1024, H=512, B=256.
// R6 = R5 + FORCED register residency for the W array.
// History: the allocator refuses to keep the 208-reg loop-invariant W array:
//   R3: AGPR-move split (VGPR=128), R4: scratch spill (19 GB/disp traffic),
//   R5: rematerialization from global (4.8 GB FETCH, VGPR=124, 1762 us).
// Fix: pass each packed W value through asm volatile("" : "+v"(x)) after init.
// The loop then consumes opaque VGPR-pinned values: remat impossible; only
// alternatives are stay-live (goal) or scratch spill (tripwire: WRITE_SIZE).
//
// Decomposition (unchanged from R5): one batch column per WG (256 WGs).
// 512 thr = 8 waves; wave w owns k-slice [64w,64w+64); lane owns 8 rows.
// h never crosses waves. W per thread: 26 pairs in VGPRs (208 regs) + 6 pairs
// in LDS (96 KB). part[] swizzled (no bank conflicts, verified R5). One
// barrier/step, part double-buffered.

#define T_SEQ    1024
#define HID      512
#define NTHREADS 512
#define NW       8            // waves
#define NCLS     10
#define RP       8            // rows per thread
#define PAIRS    32           // f16 pairs per wave k-slice (64 k)
#define PREG     26           // pairs 0..25 in VGPRs
#define PSTRIDE  576          // padded part row: 512 + 16*4 pad, 16B-aligned

typedef _Float16 half2_t __attribute__((ext_vector_type(2)));

__device__ __forceinline__ unsigned int pack2(float a, float b) {
    half2_t h = {(_Float16)a, (_Float16)b};
    return __builtin_bit_cast(unsigned int, h);
}

__device__ __forceinline__ float dot2(unsigned int w, unsigned int h, float acc) {
#if __has_builtin(__builtin_amdgcn_fdot2)
    return __builtin_amdgcn_fdot2(__builtin_bit_cast(half2_t, w),
                                  __builtin_bit_cast(half2_t, h), acc, false);
#else
    half2_t wv = __builtin_bit_cast(half2_t, w), hv = __builtin_bit_cast(half2_t, h);
    return acc + (float)wv.x * (float)hv.x + (float)wv.y * (float)hv.y;
#endif
}

// Bank-balanced padded index into a part row (multiple-of-4 => float4 stays
// 16 B aligned; spreads the 8-row groups across all 32 banks).
__device__ __forceinline__ int pidx(int row) { return row + ((row >> 5) << 2); }

__global__ __attribute__((amdgpu_flat_work_group_size(NTHREADS, NTHREADS)))
           __attribute__((amdgpu_waves_per_eu(2, 2)))
void rnn_persist(
    const float* __restrict__ x, const float* __restrict__ h_init,
    const float* __restrict__ W_hx, const float* __restrict__ W_hh,
    const float* __restrict__ b_h, const float* __restrict__ W_ph,
    const float* __restrict__ b_p, float* __restrict__ out)
{
    __shared__ uint4  Wl4[NW * RP * 64];       // 64 KB: pairs 26..29
    __shared__ uint2  Wl2[NW * RP * 64];       // 32 KB: pairs 30..31
    __shared__ float  part[2][NW][PSTRIDE];    // 36 KB: partials, dbuf, swizzled
    __shared__ float  x_s[T_SEQ];              //  4 KB
    __shared__ _Float16 hs[HID];               //  1 KB: hs[64w+j] = wave w's slice

    const int tid  = threadIdx.x;
    const int b    = blockIdx.x;
    const int w    = tid >> 6;                 // wave = k-slice owner
    const int lane = tid & 63;

    for (int i = tid; i < T_SEQ; i += NTHREADS) x_s[i] = x[(size_t)b * T_SEQ + i];

    const float whx = W_hx[tid];               // thread owns output row `tid`
    const float bh  = b_h[tid];
    hs[tid] = (_Float16)h_init[tid];

    // Load W slice: rows 8*lane..8*lane+7, cols [64w, 64w+64). Pack straight
    // into the destination registers (low peak pressure during init).
    unsigned int wreg[RP][PREG];               // 208 VGPRs
    #pragma unroll
    for (int r = 0; r < RP; ++r) {
        const float4* row = (const float4*)(W_hh + (size_t)(RP * lane + r) * HID + 64 * w);
        #pragma unroll
        for (int q = 0; q < 13; ++q) {         // pairs 0..25
            float4 v = row[q];
            wreg[r][2 * q]     = pack2(v.x, v.y);
            wreg[r][2 * q + 1] = pack2(v.z, v.w);
        }
        float4 v13 = row[13], v14 = row[14], v15 = row[15];
        Wl4[(w * RP + r) * 64 + lane] =
            make_uint4(pack2(v13.x, v13.y), pack2(v13.z, v13.w),
                       pack2(v14.x, v14.y), pack2(v14.z, v14.w));
        Wl2[(w * RP + r) * 64 + lane] =
            make_uint2(pack2(v15.x, v15.y), pack2(v15.z, v15.w));
#if __has_builtin(__builtin_amdgcn_sched_barrier)
        __builtin_amdgcn_sched_barrier(0);     // keep init-phase pressure low
#endif
    }

    // ---- THE PIN ----  Opaque identity: each W value's definition becomes an
    // asm result in a VGPR. No rematerialization possible; allocator must keep
    // it live (or scratch-spill -> visible in WRITE_SIZE).
    #pragma unroll
    for (int r = 0; r < RP; ++r)
        #pragma unroll
        for (int p = 0; p < PREG; ++p)
            asm volatile("" : "+v"(wreg[r][p]));

    __syncthreads();

    const unsigned int* hsw = (const unsigned int*)hs + w * PAIRS;  // 32 pairs

    float hval = 0.0f;
    for (int t = 0; t < T_SEQ; ++t) {
        const int buf = t & 1;

        float acc[RP];
        #pragma unroll
        for (int r = 0; r < RP; ++r) acc[r] = 0.0f;

        // Pairs 0..25 from registers; h pair = wave-uniform LDS read (broadcast;
        // consecutive addresses -> compiler can merge to b64/b128).
        #pragma unroll
        for (int p = 0; p < PREG; ++p) {
            unsigned int hp = hsw[p];
            #pragma unroll
            for (int r = 0; r < RP; ++r) acc[r] = dot2(wreg[r][p], hp, acc[r]);
        }
        // Pairs 26..31 from LDS (conflict-free b128 + b64 strides).
        {
            unsigned int h0 = hsw[26], h1 = hsw[27], h2 = hsw[28],
                         h3 = hsw[29], h4 = hsw[30], h5 = hsw[31];
            #pragma unroll
            for (int r = 0; r < RP; ++r) {
                uint4 wq = Wl4[(w * RP + r) * 64 + lane];
                uint2 wd = Wl2[(w * RP + r) * 64 + lane];
                acc[r] = dot2(wq.x, h0, acc[r]);
                acc[r] = dot2(wq.y, h1, acc[r]);
                acc[r] = dot2(wq.z, h2, acc[r]);
                acc[r] = dot2(wq.w, h3, acc[r]);
                acc[r] = dot2(wd.x, h4, acc[r]);
                acc[r] = dot2(wd.y, h5, acc[r]);
            }
        }

        // Partials for rows 8*lane..8*lane+7, swizzled (bank-balanced).
        *(float4*)&part[buf][w][pidx(RP * lane)]     = make_float4(acc[0], acc[1], acc[2], acc[3]);
        *(float4*)&part[buf][w][pidx(RP * lane + 4)] = make_float4(acc[4], acc[5], acc[6], acc[7]);

        __syncthreads();   // partials visible; dbuf => one barrier/step is safe

        // Reduce: thread `tid` owns row `tid`.
        float s = whx * x_s[t] + bh;
        const int pi = pidx(tid);
        #pragma unroll
        for (int j = 0; j < NW; ++j) s += part[buf][j][pi];

        // tanh(a) = 1 - 2/(e^{2a}+1)  (exact at +/-inf of exp)
        hval = 1.0f - 2.0f / (__expf(2.0f * s) + 1.0f);
        hs[tid] = (_Float16)hval;   // consumed only by this thread's own wave
    }

    // Epilogue: p = W_ph @ h_last + b_p (h_last f32 staged in x_s).
    __syncthreads();
    x_s[tid] = hval;
    __syncthreads();

    for (int c = w; c < NCLS; c += NW) {
        float s = 0.0f;
        #pragma unroll
        for (int j = 0; j < 8; ++j) {
            int r = lane + 64 * j;
            s += W_ph[c * HID + r] * x_s[r];
        }
        #pragma unroll
        for (int off = 32; off; off >>= 1) s += __shfl_down(s, off, 64);
        if (lane == 0) out[b * NCLS + c] = s + b_p[c];
    }
}

extern "C" void kernel_launch(void* const* d_in, const int* in_sizes, int n_in,
                              void* d_out, int out_size, void* d_ws, size_t ws_size,
                              hipStream_t stream) {
    const float* x      = (const float*)d_in[0];
    const float* h_init = (const float*)d_in[1];
    const float* W_hx   = (const float*)d_in[2];
    const float* W_hh   = (const float*)d_in[3];
    const float* b_h    = (const float*)d_in[4];
    const float* W_ph   = (const float*)d_in[5];
    const float* b_p    = (const float*)d_in[6];
    float* out = (float*)d_out;

    const int B = in_sizes[0] / T_SEQ;   // 256 batch columns -> 256 workgroups
    rnn_persist<<<B, NTHREADS, 0, stream>>>(x, h_init, W_hx, W_hh, b_h, W_ph, b_p, out);
}

// Round 7
// 1589.182 us; speedup vs baseline: 1.1116x; 1.1116x over previous
//
#include <hip/hip_runtime.h>

// VanillaRNN: h_{t+1} = tanh(W_hx x_t + W_hh h_t + b_h), T=1024, H=512, B=256.
// R7 = R6 with the LDS h-broadcast replaced by intra-wave SGPR broadcast.
// Model (R6 counters): step=4140 cyc; LDS pipe ~2600 cyc/CU/step dominates
// (uniform b128 reads are NOT free: full return-path cost, ~12 cyc each, x8
// waves). W is fully resident (124 arch VGPR + ~132 AGPR = 256 unified; the
// 4.8 GB FETCH is NOT data - suspect I$ streaming from an unrolled t-loop).
// Changes:
//  1. h-slice broadcast: wave w needs h[64w..64w+64) = its OWN lanes' hval.
//     cvt to f16 -> 2 shfl to form pairs in lanes 0..31 -> 32 v_readlane ->
//     SGPRs -> dot2 reads h from SGPR (VOP3P: 1 SGPR src allowed). Removes
//     8x b128/wave/step LDS (~770 cyc/CU) + hs[] array + its store.
//  2. #pragma unroll 1 on the t-loop (I$-thrash test for the 4.8 GB FETCH).
// Decomposition unchanged: 1 column/WG, 512 thr = 8 waves, wave w owns k-slice
// [64w,64w+64), lane owns 8 rows; W: 26 pairs/row in regs + 6 pairs/row in LDS
// (96 KB); part[] swizzled f32 partials, double-buffered, one barrier/step.

#define T_SEQ    1024
#define HID      512
#define NTHREADS 512
#define NW       8            // waves
#define NCLS     10
#define RP       8            // rows per thread
#define PAIRS    32           // f16 pairs per wave k-slice (64 k)
#define PREG     26           // pairs 0..25 in VGPRs
#define PSTRIDE  576          // padded part row: 512 + 16*4 pad, 16B-aligned

typedef _Float16 half2_t __attribute__((ext_vector_type(2)));

__device__ __forceinline__ unsigned int pack2(float a, float b) {
    half2_t h = {(_Float16)a, (_Float16)b};
    return __builtin_bit_cast(unsigned int, h);
}

__device__ __forceinline__ float dot2(unsigned int w, unsigned int h, float acc) {
#if __has_builtin(__builtin_amdgcn_fdot2)
    return __builtin_amdgcn_fdot2(__builtin_bit_cast(half2_t, w),
                                  __builtin_bit_cast(half2_t, h), acc, false);
#else
    half2_t wv = __builtin_bit_cast(half2_t, w), hv = __builtin_bit_cast(half2_t, h);
    return acc + (float)wv.x * (float)hv.x + (float)wv.y * (float)hv.y;
#endif
}

__device__ __forceinline__ unsigned int bcast(unsigned int v, int lane) {
#if __has_builtin(__builtin_amdgcn_readlane)
    return __builtin_amdgcn_readlane(v, lane);   // -> SGPR, uniform
#else
    return __shfl((int)v, lane, 64);
#endif
}

// Bank-balanced padded index into a part row (multiple-of-4 => float4 stays
// 16 B aligned; spreads the 8-row groups across all 32 banks).
__device__ __forceinline__ int pidx(int row) { return row + ((row >> 5) << 2); }

__global__ __attribute__((amdgpu_flat_work_group_size(NTHREADS, NTHREADS)))
           __attribute__((amdgpu_waves_per_eu(2, 2)))
void rnn_persist(
    const float* __restrict__ x, const float* __restrict__ h_init,
    const float* __restrict__ W_hx, const float* __restrict__ W_hh,
    const float* __restrict__ b_h, const float* __restrict__ W_ph,
    const float* __restrict__ b_p, float* __restrict__ out)
{
    __shared__ uint4  Wl4[NW * RP * 64];       // 64 KB: pairs 26..29
    __shared__ uint2  Wl2[NW * RP * 64];       // 32 KB: pairs 30..31
    __shared__ float  part[2][NW][PSTRIDE];    // 36 KB: partials, dbuf, swizzled
    __shared__ float  x_s[T_SEQ];              //  4 KB

    const int tid  = threadIdx.x;
    const int b    = blockIdx.x;
    const int w    = tid >> 6;                 // wave = k-slice owner
    const int lane = tid & 63;

    for (int i = tid; i < T_SEQ; i += NTHREADS) x_s[i] = x[(size_t)b * T_SEQ + i];

    const float whx = W_hx[tid];               // thread owns output row `tid`
    const float bh  = b_h[tid];

    // Load W slice: rows 8*lane..8*lane+7, cols [64w, 64w+64). Pack straight
    // into the destination registers (low peak pressure during init).
    unsigned int wreg[RP][PREG];               // 208 regs (arch VGPR + AGPR)
    #pragma unroll
    for (int r = 0; r < RP; ++r) {
        const float4* row = (const float4*)(W_hh + (size_t)(RP * lane + r) * HID + 64 * w);
        #pragma unroll
        for (int q = 0; q < 13; ++q) {         // pairs 0..25
            float4 v = row[q];
            wreg[r][2 * q]     = pack2(v.x, v.y);
            wreg[r][2 * q + 1] = pack2(v.z, v.w);
        }
        float4 v13 = row[13], v14 = row[14], v15 = row[15];
        Wl4[(w * RP + r) * 64 + lane] =
            make_uint4(pack2(v13.x, v13.y), pack2(v13.z, v13.w),
                       pack2(v14.x, v14.y), pack2(v14.z, v14.w));
        Wl2[(w * RP + r) * 64 + lane] =
            make_uint2(pack2(v15.x, v15.y), pack2(v15.z, v15.w));
#if __has_builtin(__builtin_amdgcn_sched_barrier)
        __builtin_amdgcn_sched_barrier(0);     // keep init-phase pressure low
#endif
    }

    // Opaque identity pin: blocks rematerialization of the packed W values.
    #pragma unroll
    for (int r = 0; r < RP; ++r)
        #pragma unroll
        for (int p = 0; p < PREG; ++p)
            asm volatile("" : "+v"(wreg[r][p]));

    __syncthreads();

    float hval = h_init[tid];                  // f32; quantized to f16 in pairs
    #pragma unroll 1                           // I$-thrash test: keep body small
    for (int t = 0; t < T_SEQ; ++t) {
        const int buf = t & 1;

        // Intra-wave h pair formation: lane p<32 gets pack2(h[64w+2p],h[64w+2p+1]).
        unsigned int hlo = __shfl(hval, 2 * lane, 64) ? 0u : 0u; // placeholder avoided
        (void)hlo;
        float alo = __shfl(hval, 2 * lane, 64);
        float ahi = __shfl(hval, 2 * lane + 1, 64);
        unsigned int hpack = pack2(alo, ahi);

        float acc[RP];
        #pragma unroll
        for (int r = 0; r < RP; ++r) acc[r] = 0.0f;

        // Pairs 0..25: W from regs, h pair broadcast via readlane -> SGPR.
        #pragma unroll
        for (int p = 0; p < PREG; ++p) {
            unsigned int hp = bcast(hpack, p);
            #pragma unroll
            for (int r = 0; r < RP; ++r) acc[r] = dot2(wreg[r][p], hp, acc[r]);
        }
        // Pairs 26..31: W from LDS (conflict-free b128 + b64 strides).
        {
            unsigned int h0 = bcast(hpack, 26), h1 = bcast(hpack, 27),
                         h2 = bcast(hpack, 28), h3 = bcast(hpack, 29),
                         h4 = bcast(hpack, 30), h5 = bcast(hpack, 31);
            #pragma unroll
            for (int r = 0; r < RP; ++r) {
                uint4 wq = Wl4[(w * RP + r) * 64 + lane];
                uint2 wd = Wl2[(w * RP + r) * 64 + lane];
                acc[r] = dot2(wq.x, h0, acc[r]);
                acc[r] = dot2(wq.y, h1, acc[r]);
                acc[r] = dot2(wq.z, h2, acc[r]);
                acc[r] = dot2(wq.w, h3, acc[r]);
                acc[r] = dot2(wd.x, h4, acc[r]);
                acc[r] = dot2(wd.y, h5, acc[r]);
            }
        }

        // Partials for rows 8*lane..8*lane+7, swizzled (bank-balanced).
        *(float4*)&part[buf][w][pidx(RP * lane)]     = make_float4(acc[0], acc[1], acc[2], acc[3]);
        *(float4*)&part[buf][w][pidx(RP * lane + 4)] = make_float4(acc[4], acc[5], acc[6], acc[7]);

        __syncthreads();   // partials visible; dbuf => one barrier/step is safe

        // Reduce: thread `tid` owns row `tid`.
        float s = whx * x_s[t] + bh;
        const int pi = pidx(tid);
        #pragma unroll
        for (int j = 0; j < NW; ++j) s += part[buf][j][pi];

        // tanh(a) = 1 - 2/(e^{2a}+1)  (exact at +/-inf of exp)
        hval = 1.0f - 2.0f / (__expf(2.0f * s) + 1.0f);
    }

    // Epilogue: p = W_ph @ h_last + b_p (h_last f32 staged in x_s).
    __syncthreads();
    x_s[tid] = hval;
    __syncthreads();

    for (int c = w; c < NCLS; c += NW) {
        float s = 0.0f;
        #pragma unroll
        for (int j = 0; j < 8; ++j) {
            int r = lane + 64 * j;
            s += W_ph[c * HID + r] * x_s[r];
        }
        #pragma unroll
        for (int off = 32; off; off >>= 1) s += __shfl_down(s, off, 64);
        if (lane == 0) out[b * NCLS + c] = s + b_p[c];
    }
}

extern "C" void kernel_launch(void* const* d_in, const int* in_sizes, int n_in,
                              void* d_out, int out_size, void* d_ws, size_t ws_size,
                              hipStream_t stream) {
    const float* x      = (const float*)d_in[0];
    const float* h_init = (const float*)d_in[1];
    const float* W_hx   = (const float*)d_in[2];
    const float* W_hh   = (const float*)d_in[3];
    const float* b_h    = (const float*)d_in[4];
    const float* W_ph   = (const float*)d_in[5];
    const float* b_p    = (const float*)d_in[6];
    float* out = (float*)d_out;

    const int B = in_sizes[0] / T_SEQ;   // 256 batch columns -> 256 workgroups
    rnn_persist<<<B, NTHREADS, 0, stream>>>(x, h_init, W_hx, W_hh, b_h, W_ph, b_p, out);
}